// Round 4
// baseline (670.416 us; speedup 1.0000x reference)
//
#include <hip/hip_runtime.h>
#include <stdint.h>

// B=4, C=192, H=W=224, WS=8, NH=6, hd=32, SHIFT=4. I/O fp32; internal bf16 MFMA.
#define HHW   224
#define CCH   192
#define SHIFT 4
#define NWIN  3136           // 4 * 28 * 28
#define NTOK  200704         // NWIN * 64
#define QN    38535168ull    // NWIN*6*64*32 elements per Q/K/VT tensor (bf16)

typedef __attribute__((ext_vector_type(8))) short bf16x8;   // MFMA A/B frag
typedef __attribute__((ext_vector_type(4))) float f32x4;    // MFMA C/D frag

__device__ __forceinline__ ushort f2bf(float f) {
    union { float f; uint32_t i; } v; v.f = f;
    uint32_t u = v.i;
    return (ushort)((u + 0x7FFFu + ((u >> 16) & 1u)) >> 16);  // RNE
}
__device__ __forceinline__ uint32_t pk2(float a, float b) {
    return (uint32_t)f2bf(a) | ((uint32_t)f2bf(b) << 16);
}

// ---------------------------------------------------------------------------
// prep_w: weights fp32 [o][c] -> bf16 image in MFMA-FRAGMENT order:
//   img[((ch*6+k)*4+quad)*6 + m][l16][j] = w[ch*96 + m*16 + l16][k*32+quad*8+j]
// so a wave's A-frag load (quad,l16 lanes) is 4 x 256B fully-coalesced runs,
// read directly from global (L2-broadcast across all blocks; no LDS, no
// barriers in the gemm).
// ---------------------------------------------------------------------------
__global__ __launch_bounds__(256) void prep_w(const float* __restrict__ w,
                                              ushort* __restrict__ wo, int nrow)
{
    int idx = blockIdx.x * 256 + threadIdx.x;
    if (idx >= nrow * 24) return;
    int rg = idx / 24, p = idx % 24;          // rg = ch*96 + m*16 + l16
    int ch = rg / 96, mr = rg % 96;
    int m = mr >> 4, l16 = mr & 15;
    int k = p >> 2, quad = p & 3;
    const float* src = w + (size_t)rg * 192 + p * 8;
    float4 a = *(const float4*)src;
    float4 b = *(const float4*)(src + 4);
    uint4 o;
    o.x = pk2(a.x, a.y); o.y = pk2(a.z, a.w);
    o.z = pk2(b.x, b.y); o.w = pk2(b.z, b.w);
    size_t out = (size_t)((((ch * 6 + k) * 4 + quad) * 6 + m) * 16 + l16) * 8;
    *(uint4*)(wo + out) = o;
}

// ---------------------------------------------------------------------------
// prep_x: x fp32 [b][c][h][w] -> X1 bf16 [win][oct][t][8ch], roll(+4) folded.
// Block = (b, hn, channel-octet). Reads FULL 896B image rows (zero over-fetch).
// Register transpose -> b128 LDS writes into XOR-swizzled [p][8ch] tile.
// Output: per (window, octet) a 1KB fully-contiguous burst.
// ---------------------------------------------------------------------------
__global__ __launch_bounds__(256) void prep_x(const float* __restrict__ x,
                                              ushort* __restrict__ xo)
{
    __shared__ ushort lt[1792 * 8];          // [p][8ch], 16B rows, swizzled
    const int blk = blockIdx.x;              // ((b*28 + hn)*24 + oct)
    const int oct = blk % 24;
    const int bh  = blk / 24;                // b*28 + hn
    const int hn  = bh % 28;
    const float* xb = x + ((size_t)(bh / 28) * CCH + oct * 8) * (HHW * HHW);

    // Read phase: task u = pixel-quad index (r = u/56, 4-col group q = u%56).
    for (int u = threadIdx.x; u < 448; u += 256) {
        int r = u / 56, q = u % 56;
        int hh = (hn * 8 + r + SHIFT) % HHW;
        int ww = (q * 4 + SHIFT) % HHW;      // %4==0, wrap lands on float4 bound
        const float* src = xb + (size_t)hh * HHW + ww;
        float4 v[8];
        #pragma unroll
        for (int c = 0; c < 8; c++)
            v[c] = *(const float4*)(src + (size_t)c * (HHW * HHW));
        #pragma unroll
        for (int i = 0; i < 4; i++) {
            int p = u * 4 + i;               // = r*224 + q*4 + i
            int sw = p ^ ((p >> 3) & 7);
            uint4 o;
            o.x = pk2(((const float*)&v[0])[i], ((const float*)&v[1])[i]);
            o.y = pk2(((const float*)&v[2])[i], ((const float*)&v[3])[i]);
            o.z = pk2(((const float*)&v[4])[i], ((const float*)&v[5])[i]);
            o.w = pk2(((const float*)&v[6])[i], ((const float*)&v[7])[i]);
            *(uint4*)&lt[sw * 8] = o;
        }
    }
    __syncthreads();

    // Write phase: per window wn, token t -> 16B; lanes t consecutive -> 1KB bursts.
    for (int u = threadIdx.x; u < 1792; u += 256) {
        int wn = u >> 6, t = u & 63;
        int p = (t >> 3) * 224 + wn * 8 + (t & 7);
        int sw = p ^ ((p >> 3) & 7);
        *(uint4*)(xo + (size_t)(bh * 28 + wn) * 12288 + oct * 512 + t * 8) =
            *(const uint4*)&lt[sw * 8];
    }
}

// ---------------------------------------------------------------------------
// GEMM: out[o][p] = bias[o] + sum_c W[o][c] * X1[p][c].  N=128 tokens/block,
// wave owns 32 tokens (2 n-frags); B-frags loaded ONCE directly from global.
// A-frags read DIRECTLY from the fragment-ordered global weight image
// (L2-broadcast). NO LDS, NO barriers -> stores are never vmcnt-drained
// mid-kernel; compiler pipelines chunks freely.
// OCH=576 input layout: [win][oct][t][8ch] (fully coalesced 16B/lane).
// OCH=192 input layout: [t][c] token rows (X2 from attn).
// ---------------------------------------------------------------------------
template<int OCH>
__global__ __launch_bounds__(256, 2) void gemm_win(
    const ushort* __restrict__ xin, const ushort* __restrict__ wbf,
    const float* __restrict__ bias,
    ushort* __restrict__ qo, ushort* __restrict__ ko, ushort* __restrict__ vto,
    float* __restrict__ dout)
{
    const int tid = threadIdx.x;
    const int wave = tid >> 6, lane = tid & 63;
    const int quad = lane >> 4, l16 = lane & 15;
    const int p0 = blockIdx.x * 128 + wave * 32;

    // B-frags: all 192 channels of this wave's 32 tokens, held in VGPRs.
    bf16x8 bfr[2][6];
    #pragma unroll
    for (int nt = 0; nt < 2; nt++) {
        int token = p0 + nt * 16 + l16;
        #pragma unroll
        for (int k = 0; k < 6; k++) {
            if (OCH == 576)   // octet layout
                bfr[nt][k] = *(const bf16x8*)(xin + (size_t)(token >> 6) * 12288
                                              + (k * 4 + quad) * 512 + (token & 63) * 8);
            else              // token-row layout
                bfr[nt][k] = *(const bf16x8*)(xin + (size_t)token * CCH + k * 32 + quad * 8);
        }
    }

    #pragma unroll
    for (int ch = 0; ch < OCH / 96; ch++) {
        const ushort* wch = wbf + (size_t)ch * (96 * 192);   // fragment-ordered chunk

        f32x4 acc[6][2];
        #pragma unroll
        for (int m = 0; m < 6; m++)
            #pragma unroll
            for (int nt = 0; nt < 2; nt++) acc[m][nt] = (f32x4){0.f, 0.f, 0.f, 0.f};

        #pragma unroll
        for (int k = 0; k < 6; k++) {
            const ushort* wk = wch + ((k * 4 + quad) * 96 + l16) * 8;
            #pragma unroll
            for (int m = 0; m < 6; m++) {
                bf16x8 afrag = *(const bf16x8*)(wk + m * 128);
                acc[m][0] = __builtin_amdgcn_mfma_f32_16x16x32_bf16(afrag, bfr[0][k], acc[m][0], 0, 0, 0);
                acc[m][1] = __builtin_amdgcn_mfma_f32_16x16x32_bf16(afrag, bfr[1][k], acc[m][1], 0, 0, 0);
            }
        }

        // Epilogue. D row = quad*4+rg (o dim), col = l16 (token dim).
        const int obase = ch * 96;
        #pragma unroll
        for (int m = 0; m < 6; m++) {
            const int o0 = obase + m * 16 + quad * 4;          // %4 == 0
            float4 bb = *(const float4*)(bias + o0);           // 16-lane broadcast, cached
            #pragma unroll
            for (int nt = 0; nt < 2; nt++) {
                int token = p0 + nt * 16 + l16;
                int win = token >> 6, t = token & 63;
                float f0 = acc[m][nt][0] + bb.x, f1 = acc[m][nt][1] + bb.y;
                float f2 = acc[m][nt][2] + bb.z, f3 = acc[m][nt][3] + bb.w;
                if (OCH == 576) {
                    const int s = o0 / 192;                    // uniform per (ch,m)
                    const int rem = o0 % 192;
                    const int h = rem >> 5, d0 = rem & 31;     // d0 %4 == 0
                    size_t wh = (size_t)win * 6 + h;
                    if (s == 2) {
                        vto[(wh * 32 + d0 + 0) * 64 + t] = f2bf(f0);
                        vto[(wh * 32 + d0 + 1) * 64 + t] = f2bf(f1);
                        vto[(wh * 32 + d0 + 2) * 64 + t] = f2bf(f2);
                        vto[(wh * 32 + d0 + 3) * 64 + t] = f2bf(f3);
                    } else {
                        uint2 pk;
                        pk.x = pk2(f0, f1);
                        pk.y = pk2(f2, f3);
                        ushort* dst = (s == 0 ? qo : ko) + (wh * 64 + t) * 32 + d0;
                        *(uint2*)dst = pk;
                    }
                } else {
                    int b = win / 784, hn = (win / 28) % 28, wn = win % 28;
                    int hh = (hn * 8 + (t >> 3) + SHIFT) % HHW;
                    int ww = (wn * 8 + (t & 7) + SHIFT) % HHW;
                    float* dst = dout + ((size_t)(b * CCH + o0) * HHW + hh) * HHW + ww;
                    dst[0] = f0; dst[(size_t)HHW * HHW] = f1;
                    dst[2 * (size_t)HHW * HHW] = f2; dst[3 * (size_t)HHW * HHW] = f3;
                }
            }
        }
    }
}

// ---------------------------------------------------------------------------
// attn: one block = one window, 6 waves = 6 heads. SWAPPED operands:
//   S^T = mfma(K, Q)  -> lane holds a q-column: 16 k-values locally, the rest
//   in the 3 quad-partner lanes -> softmax = local 16-reduce + 2 shuffles.
//   P stored packed (b64) into XOR-swizzled pt[q][64] (bank-uniform writes
//   AND b128 reads; stride 64 -> LDS 48KB -> 3 blocks/CU).
//   O^T = mfma(V^T, P^T) -> accumulator regs = consecutive channels -> packed
//   uint2 X2 stores.
// X2 bf16 [t][c] ALIASED onto Q. Safe: all Q/K/V loads issue before
// __syncthreads (vmcnt(0) drain); X2 stores strictly after.
// ---------------------------------------------------------------------------
__global__ __launch_bounds__(384, 4) void attn_win(
    ushort* qx2,                                   // Q in / X2 out (aliased)
    const ushort* __restrict__ k, const ushort* __restrict__ vt)
{
    __shared__ ushort pt[6][64 * 64];   // per-head swizzled P [q][k]

    const int tid = threadIdx.x;
    const int h = tid >> 6, lane = tid & 63;
    const int quad = lane >> 4, l16 = lane & 15;
    const int win = blockIdx.x;

    const ushort* qp = qx2 + (size_t)(win * 6 + h) * 2048;
    const ushort* kp = k   + (size_t)(win * 6 + h) * 2048;
    const ushort* vp = vt  + (size_t)(win * 6 + h) * 2048;

    // K rows as A-frags, Q as B-frags, V^T rows as A-frags (all pre-barrier).
    bf16x8 kf[4], qf[4], vf[2][2];
    #pragma unroll
    for (int nt = 0; nt < 4; nt++) kf[nt] = *(const bf16x8*)&kp[(nt * 16 + l16) * 32 + quad * 8];
    #pragma unroll
    for (int nt = 0; nt < 4; nt++) qf[nt] = *(const bf16x8*)&qp[(nt * 16 + l16) * 32 + quad * 8];
    #pragma unroll
    for (int md = 0; md < 2; md++)
        #pragma unroll
        for (int ks = 0; ks < 2; ks++)
            vf[md][ks] = *(const bf16x8*)&vp[(md * 16 + l16) * 64 + ks * 32 + quad * 8];

    const float SC = 0.25506953149031837f;   // (1/sqrt(32)) * log2(e)
    ushort* ph = pt[h];

    // S^T tiles per q-pair: row = k (quad*4+rg), col = q (l16).
    #pragma unroll
    for (int nq = 0; nq < 4; nq += 2) {
        f32x4 sc[2][4];
        #pragma unroll
        for (int j = 0; j < 2; j++)
            #pragma unroll
            for (int mk = 0; mk < 4; mk++) {
                sc[j][mk] = (f32x4){0.f, 0.f, 0.f, 0.f};
                sc[j][mk] = __builtin_amdgcn_mfma_f32_16x16x32_bf16(kf[mk], qf[nq + j], sc[j][mk], 0, 0, 0);
            }
        #pragma unroll
        for (int j = 0; j < 2; j++) {
            float mx = sc[j][0][0];
            #pragma unroll
            for (int mk = 0; mk < 4; mk++)
                #pragma unroll
                for (int rg = 0; rg < 4; rg++) mx = fmaxf(mx, sc[j][mk][rg]);
            mx = fmaxf(mx, __shfl_xor(mx, 16, 64));
            mx = fmaxf(mx, __shfl_xor(mx, 32, 64));
            float e[4][4];
            float sm = 0.f;
            #pragma unroll
            for (int mk = 0; mk < 4; mk++)
                #pragma unroll
                for (int rg = 0; rg < 4; rg++) {
                    e[mk][rg] = exp2f((sc[j][mk][rg] - mx) * SC);
                    sm += e[mk][rg];
                }
            sm += __shfl_xor(sm, 16, 64);
            sm += __shfl_xor(sm, 32, 64);
            float r = __builtin_amdgcn_rcpf(sm);
            const int q = (nq + j) * 16 + l16;
            const int sx = q & 7;
            ushort* row = ph + q * 64;
            #pragma unroll
            for (int mk = 0; mk < 4; mk++) {
                uint2 w;
                w.x = pk2(e[mk][0] * r, e[mk][1] * r);
                w.y = pk2(e[mk][2] * r, e[mk][3] * r);
                int s0 = mk * 2 + (quad >> 1);
                *(uint2*)(row + (((s0 ^ sx) << 3) + (quad & 1) * 4)) = w;
            }
        }
    }
    __syncthreads();   // drains all global loads; X2 stores are after this

    // O^T = V^T (A) x P^T (B from pt): row = d, col = q.
    f32x4 o[2][4];
    #pragma unroll
    for (int md = 0; md < 2; md++)
        #pragma unroll
        for (int nq = 0; nq < 4; nq++) o[md][nq] = (f32x4){0.f, 0.f, 0.f, 0.f};
    #pragma unroll
    for (int ks = 0; ks < 2; ks++)
        #pragma unroll
        for (int nq = 0; nq < 4; nq++) {
            const int q = nq * 16 + l16;
            bf16x8 pf = *(const bf16x8*)(ph + q * 64 + ((((ks * 4 + quad) ^ (q & 7))) << 3));
            #pragma unroll
            for (int md = 0; md < 2; md++)
                o[md][nq] = __builtin_amdgcn_mfma_f32_16x16x32_bf16(vf[md][ks], pf, o[md][nq], 0, 0, 0);
        }

    // X2[t][c] bf16: 4 consecutive channels per acc frag -> packed 8B stores.
    ushort* x2 = qx2 + (size_t)win * 12288;
    #pragma unroll
    for (int md = 0; md < 2; md++)
        #pragma unroll
        for (int nq = 0; nq < 4; nq++) {
            const int q = nq * 16 + l16;
            const int c = h * 32 + md * 16 + quad * 4;
            uint2 w;
            w.x = pk2(o[md][nq][0], o[md][nq][1]);
            w.y = pk2(o[md][nq][2], o[md][nq][3]);
            *(uint2*)(x2 + q * CCH + c) = w;
        }
}

extern "C" void kernel_launch(void* const* d_in, const int* in_sizes, int n_in,
                              void* d_out, int out_size, void* d_ws, size_t ws_size,
                              hipStream_t stream) {
    const float* x      = (const float*)d_in[0];
    const float* w_qkv  = (const float*)d_in[1];
    const float* b_qkv  = (const float*)d_in[2];
    const float* w_proj = (const float*)d_in[3];
    const float* b_proj = (const float*)d_in[4];
    float* out = (float*)d_out;
    ushort* ws = (ushort*)d_ws;

    ushort* X1 = (ushort*)d_out;       // 77 MB bf16 region inside d_out (154 MB)
    ushort* WQ = (ushort*)d_out + QN;  // bf16 qkv weights in d_out's spare half
                                       // (dead until final gemm writes out)
    ushort* Q  = ws;                   // [win][h][64][32] bf16; becomes X2 [win][t][c]
    ushort* K  = ws + QN;
    ushort* VT = ws + 2 * QN;          // [win][h][32][64] bf16 (ws total 231 MB)
    ushort* WP = VT;                   // bf16 proj weights reuse VT (dead post-attn)

    prep_w       <<<54, 256, 0, stream>>>(w_qkv, WQ, 576);
    prep_x       <<<4 * 28 * 24, 256, 0, stream>>>(x, X1);
    gemm_win<576><<<NTOK / 128, 256, 0, stream>>>(X1, WQ, b_qkv, Q, K, VT, nullptr);
    attn_win     <<<NWIN, 384, 0, stream>>>(Q, K, VT);
    prep_w       <<<18, 256, 0, stream>>>(w_proj, WP, 192);
    gemm_win<192><<<NTOK / 128, 256, 0, stream>>>(Q, WP, b_proj, nullptr, nullptr, nullptr, out);
}

// Round 5
// 506.947 us; speedup vs baseline: 1.3225x; 1.3225x over previous
//
#include <hip/hip_runtime.h>
#include <stdint.h>

// B=4, C=192, H=W=224, WS=8, NH=6, hd=32, SHIFT=4. I/O fp32; internal bf16 MFMA.
#define HHW   224
#define CCH   192
#define SHIFT 4
#define NWIN  3136           // 4 * 28 * 28
#define NTOK  200704         // NWIN * 64
#define QN    38535168ull    // NWIN*64*192 elements (bf16) = 77 MB region

typedef __attribute__((ext_vector_type(8))) short bf16x8;   // MFMA A/B frag
typedef __attribute__((ext_vector_type(4))) float f32x4;    // MFMA C/D frag

__device__ __forceinline__ ushort f2bf(float f) {
    union { float f; uint32_t i; } v; v.f = f;
    uint32_t u = v.i;
    return (ushort)((u + 0x7FFFu + ((u >> 16) & 1u)) >> 16);  // RNE
}
__device__ __forceinline__ uint32_t pk2(float a, float b) {
    return (uint32_t)f2bf(a) | ((uint32_t)f2bf(b) << 16);
}

// ---------------------------------------------------------------------------
// prep_w: weights fp32 [o][c] -> bf16 image in MFMA-FRAGMENT order:
//   img[(((ch*6+k)*4+quad)*6 + m)*16 + l16][8] = w[ch*96+m*16+l16][k*32+quad*8+..]
// Consumers stage one 36 KB chunk LINEARLY via global_load_lds; a wave's
// A-frag read is then 16 consecutive 16B lanes -> naturally conflict-free.
// ---------------------------------------------------------------------------
__global__ __launch_bounds__(256) void prep_w(const float* __restrict__ w,
                                              ushort* __restrict__ wo, int nrow)
{
    int idx = blockIdx.x * 256 + threadIdx.x;
    if (idx >= nrow * 24) return;
    int rg = idx / 24, p = idx % 24;          // rg = ch*96 + m*16 + l16
    int ch = rg / 96, mr = rg % 96;
    int m = mr >> 4, l16 = mr & 15;
    int k = p >> 2, quad = p & 3;
    const float* src = w + (size_t)rg * 192 + p * 8;
    float4 a = *(const float4*)src;
    float4 b = *(const float4*)(src + 4);
    uint4 o;
    o.x = pk2(a.x, a.y); o.y = pk2(a.z, a.w);
    o.z = pk2(b.x, b.y); o.w = pk2(b.z, b.w);
    size_t out = (size_t)((((ch * 6 + k) * 4 + quad) * 6 + m) * 16 + l16) * 8;
    *(uint4*)(wo + out) = o;
}

// ---------------------------------------------------------------------------
// prep_x: x fp32 [b][c][h][w] -> X1 bf16 [win][oct][t][8ch], roll(+4) folded.
// Block = (b, hn, channel-octet). Reads FULL 896B image rows (zero over-fetch).
// Register transpose -> b128 LDS writes into XOR-swizzled [p][8ch] tile.
// Output: per (window, octet) a 1KB fully-contiguous burst.
// ---------------------------------------------------------------------------
__global__ __launch_bounds__(256) void prep_x(const float* __restrict__ x,
                                              ushort* __restrict__ xo)
{
    __shared__ ushort lt[1792 * 8];          // [p][8ch], 16B rows, swizzled
    const int blk = blockIdx.x;              // ((b*28 + hn)*24 + oct)
    const int oct = blk % 24;
    const int bh  = blk / 24;                // b*28 + hn
    const int hn  = bh % 28;
    const float* xb = x + ((size_t)(bh / 28) * CCH + oct * 8) * (HHW * HHW);

    for (int u = threadIdx.x; u < 448; u += 256) {
        int r = u / 56, q = u % 56;
        int hh = (hn * 8 + r + SHIFT) % HHW;
        int ww = (q * 4 + SHIFT) % HHW;      // %4==0, wrap lands on float4 bound
        const float* src = xb + (size_t)hh * HHW + ww;
        float4 v[8];
        #pragma unroll
        for (int c = 0; c < 8; c++)
            v[c] = *(const float4*)(src + (size_t)c * (HHW * HHW));
        #pragma unroll
        for (int i = 0; i < 4; i++) {
            int p = u * 4 + i;               // = r*224 + q*4 + i
            int sw = p ^ ((p >> 3) & 7);
            uint4 o;
            o.x = pk2(((const float*)&v[0])[i], ((const float*)&v[1])[i]);
            o.y = pk2(((const float*)&v[2])[i], ((const float*)&v[3])[i]);
            o.z = pk2(((const float*)&v[4])[i], ((const float*)&v[5])[i]);
            o.w = pk2(((const float*)&v[6])[i], ((const float*)&v[7])[i]);
            *(uint4*)&lt[sw * 8] = o;
        }
    }
    __syncthreads();

    for (int u = threadIdx.x; u < 1792; u += 256) {
        int wn = u >> 6, t = u & 63;
        int p = (t >> 3) * 224 + wn * 8 + (t & 7);
        int sw = p ^ ((p >> 3) & 7);
        *(uint4*)(xo + (size_t)(bh * 28 + wn) * 12288 + oct * 512 + t * 8) =
            *(const uint4*)&lt[sw * 8];
    }
}

// ---------------------------------------------------------------------------
// qkv_attn_win: FUSED qkv-gemm + window attention. Block = 1 window, 6 waves.
// Q/K/V never touch HBM: gemm writes them to LDS, attention reads LDS.
//
// Gemm phase: 6 chunks x 96 weight rows, double-buffered global_load_lds
// staging (36 KB each); wave w owns o-rows [w*16, w*16+16) x all 64 tokens
// (24 MFMA/chunk). No global stores in the loop -> barrier drains are cheap.
// Q,K in LDS [h][t][d] with 80B row pitch (pitch 20 words: both the packed
// uint2 writes and the b128 frag reads are conflict-free); V in [h][d][t]
// with 144B pitch (same property).
// Attn phase: wave = head; identical math to the verified round-3 attn
// (swapped-operand S^T = mfma(K,Q), 2-shuffle softmax, swizzled P in LDS
// aliasing the dead weight buffers, O^T = mfma(V^T,P^T)); X2 [t][c] to HBM.
// ---------------------------------------------------------------------------
__global__ __launch_bounds__(384, 1) void qkv_attn_win(
    const ushort* __restrict__ xin,   // X1 [win][oct][t][8]
    const ushort* __restrict__ wbf,   // fragment-order 576-row weight image
    const float* __restrict__ bias,   // b_qkv
    ushort* __restrict__ x2o)         // X2 [win*64+t][192]
{
    // LDS (bytes): [0,73728) W dbuf (2x36864; aliased by P 6x8192 in attn)
    //              [73728,104448) Q 6h x 64t x 80B
    //              [104448,135168) K same
    //              [135168,162816) V 6h x 32d x 144B
    __shared__ char smem[162816];
    char* qb = smem + 73728;
    char* kb = smem + 104448;
    char* vb = smem + 135168;

    const int tid = threadIdx.x;
    const int wave = tid / 64, lane = tid & 63;
    const int quad = lane >> 4, l16 = lane & 15;
    const int win = blockIdx.x;

    // B-frags: all 64 tokens x 192 ch of this window (24 KB, L1-resident).
    bf16x8 bfr[4][6];
    const ushort* xw = xin + (size_t)win * 12288;
    #pragma unroll
    for (int nt = 0; nt < 4; nt++)
        #pragma unroll
        for (int k = 0; k < 6; k++)
            bfr[nt][k] = *(const bf16x8*)(xw + (k * 4 + quad) * 512 + (nt * 16 + l16) * 8);

    // Stage chunk 0 into buffer 0 (6 x 1KB per wave, linear).
    #pragma unroll
    for (int it = 0; it < 6; it++) {
        int off = it * 3072 + wave * 512;            // ushort units, wave-uniform
        __builtin_amdgcn_global_load_lds(
            (const __attribute__((address_space(1))) void*)(wbf + off + lane * 8),
            (__attribute__((address_space(3))) void*)(smem + off * 2), 16, 0, 0);
    }
    __syncthreads();

    #pragma unroll
    for (int ch = 0; ch < 6; ch++) {
        if (ch < 5) {
            const ushort* wsrc = wbf + (size_t)(ch + 1) * 18432;
            char* dbuf = smem + ((ch + 1) & 1) * 36864;
            #pragma unroll
            for (int it = 0; it < 6; it++) {
                int off = it * 3072 + wave * 512;
                __builtin_amdgcn_global_load_lds(
                    (const __attribute__((address_space(1))) void*)(wsrc + off + lane * 8),
                    (__attribute__((address_space(3))) void*)(dbuf + off * 2), 16, 0, 0);
            }
        }
        const ushort* cur = (const ushort*)(smem + (ch & 1) * 36864);

        f32x4 acc[4];
        #pragma unroll
        for (int nt = 0; nt < 4; nt++) acc[nt] = (f32x4){0.f, 0.f, 0.f, 0.f};
        #pragma unroll
        for (int k = 0; k < 6; k++) {
            bf16x8 af = *(const bf16x8*)(cur + ((k * 4 + quad) * 96 + wave * 16 + l16) * 8);
            #pragma unroll
            for (int nt = 0; nt < 4; nt++)
                acc[nt] = __builtin_amdgcn_mfma_f32_16x16x32_bf16(af, bfr[nt][k], acc[nt], 0, 0, 0);
        }

        // Epilogue -> LDS. o = ch*96 + wave*16 + quad*4 + rg, t = nt*16+l16.
        const int o0c = ch * 96 + wave * 16 + quad * 4;
        float4 bb = *(const float4*)(bias + o0c);
        const int rem = (ch & 1) * 96 + wave * 16 + quad * 4;   // o0c % 192
        const int h = rem >> 5, d0 = rem & 31;                  // d0 % 4 == 0
        #pragma unroll
        for (int nt = 0; nt < 4; nt++) {
            const int t = nt * 16 + l16;
            float f0 = acc[nt][0] + bb.x, f1 = acc[nt][1] + bb.y;
            float f2 = acc[nt][2] + bb.z, f3 = acc[nt][3] + bb.w;
            if (ch < 4) {                      // s = ch>>1: 0=Q, 1=K
                char* base = (ch < 2 ? qb : kb);
                uint2 w;
                w.x = pk2(f0, f1); w.y = pk2(f2, f3);
                *(uint2*)(base + h * 5120 + t * 80 + d0 * 2) = w;
            } else {                           // s = 2: V [d][t], pitch 72 ushorts
                ushort* vh = (ushort*)(vb + h * 4608);
                vh[(d0 + 0) * 72 + t] = f2bf(f0);
                vh[(d0 + 1) * 72 + t] = f2bf(f1);
                vh[(d0 + 2) * 72 + t] = f2bf(f2);
                vh[(d0 + 3) * 72 + t] = f2bf(f3);
            }
        }
        __syncthreads();   // staging drained + QKV writes visible
    }

    // ---- attention phase: wave = head ----
    const int h = wave;
    bf16x8 kf[4], qf[4], vf[2][2];
    #pragma unroll
    for (int nt = 0; nt < 4; nt++)
        qf[nt] = *(const bf16x8*)(qb + h * 5120 + (nt * 16 + l16) * 80 + quad * 16);
    #pragma unroll
    for (int nt = 0; nt < 4; nt++)
        kf[nt] = *(const bf16x8*)(kb + h * 5120 + (nt * 16 + l16) * 80 + quad * 16);
    #pragma unroll
    for (int md = 0; md < 2; md++)
        #pragma unroll
        for (int ks = 0; ks < 2; ks++)
            vf[md][ks] = *(const bf16x8*)(vb + h * 4608 + (md * 16 + l16) * 144 + ks * 64 + quad * 16);

    const float SC = 0.25506953149031837f;   // (1/sqrt(32)) * log2(e)
    ushort* ph = (ushort*)smem + h * 4096;   // P tile aliases dead W buffers

    #pragma unroll
    for (int nq = 0; nq < 4; nq += 2) {
        f32x4 sc[2][4];
        #pragma unroll
        for (int j = 0; j < 2; j++)
            #pragma unroll
            for (int mk = 0; mk < 4; mk++) {
                sc[j][mk] = (f32x4){0.f, 0.f, 0.f, 0.f};
                sc[j][mk] = __builtin_amdgcn_mfma_f32_16x16x32_bf16(kf[mk], qf[nq + j], sc[j][mk], 0, 0, 0);
            }
        #pragma unroll
        for (int j = 0; j < 2; j++) {
            float mx = sc[j][0][0];
            #pragma unroll
            for (int mk = 0; mk < 4; mk++)
                #pragma unroll
                for (int rg = 0; rg < 4; rg++) mx = fmaxf(mx, sc[j][mk][rg]);
            mx = fmaxf(mx, __shfl_xor(mx, 16, 64));
            mx = fmaxf(mx, __shfl_xor(mx, 32, 64));
            float e[4][4];
            float sm = 0.f;
            #pragma unroll
            for (int mk = 0; mk < 4; mk++)
                #pragma unroll
                for (int rg = 0; rg < 4; rg++) {
                    e[mk][rg] = exp2f((sc[j][mk][rg] - mx) * SC);
                    sm += e[mk][rg];
                }
            sm += __shfl_xor(sm, 16, 64);
            sm += __shfl_xor(sm, 32, 64);
            float r = __builtin_amdgcn_rcpf(sm);
            const int q = (nq + j) * 16 + l16;
            const int sx = q & 7;
            ushort* row = ph + q * 64;
            #pragma unroll
            for (int mk = 0; mk < 4; mk++) {
                uint2 w;
                w.x = pk2(e[mk][0] * r, e[mk][1] * r);
                w.y = pk2(e[mk][2] * r, e[mk][3] * r);
                int s0 = mk * 2 + (quad >> 1);
                *(uint2*)(row + (((s0 ^ sx) << 3) + (quad & 1) * 4)) = w;
            }
        }
    }
    // P is written and read by the same wave only -> no barrier needed.

    f32x4 o[2][4];
    #pragma unroll
    for (int md = 0; md < 2; md++)
        #pragma unroll
        for (int nq = 0; nq < 4; nq++) o[md][nq] = (f32x4){0.f, 0.f, 0.f, 0.f};
    #pragma unroll
    for (int ks = 0; ks < 2; ks++)
        #pragma unroll
        for (int nq = 0; nq < 4; nq++) {
            const int q = nq * 16 + l16;
            bf16x8 pf = *(const bf16x8*)(ph + q * 64 + ((((ks * 4 + quad) ^ (q & 7))) << 3));
            #pragma unroll
            for (int md = 0; md < 2; md++)
                o[md][nq] = __builtin_amdgcn_mfma_f32_16x16x32_bf16(vf[md][ks], pf, o[md][nq], 0, 0, 0);
        }

    // X2[t][c] bf16: packed 8B stores.
    ushort* x2 = x2o + (size_t)win * 12288;
    #pragma unroll
    for (int md = 0; md < 2; md++)
        #pragma unroll
        for (int nq = 0; nq < 4; nq++) {
            const int q = nq * 16 + l16;
            const int c = h * 32 + md * 16 + quad * 4;
            uint2 w;
            w.x = pk2(o[md][nq][0], o[md][nq][1]);
            w.y = pk2(o[md][nq][2], o[md][nq][3]);
            *(uint2*)(x2 + q * CCH + c) = w;
        }
}

// ---------------------------------------------------------------------------
// gemm_proj: out = X2 @ Wproj + b (round-3 LDS-staged structure, fragment-
// order weight image). 128 tokens/block, wave owns 32 tokens; 2 chunks of 96
// rows staged via global_load_lds; conflict-free linear frag reads.
// ---------------------------------------------------------------------------
__global__ __launch_bounds__(256, 3) void gemm_proj(
    const ushort* __restrict__ xin, const ushort* __restrict__ wbf,
    const float* __restrict__ bias, float* __restrict__ dout)
{
    __shared__ ushort wc[96 * 192];  // 36864 B weight chunk

    const int tid = threadIdx.x;
    const int wave = tid >> 6, lane = tid & 63;
    const int quad = lane >> 4, l16 = lane & 15;
    const int p0 = blockIdx.x * 128 + wave * 32;

    #pragma unroll
    for (int it = 0; it < 9; it++) {
        int off = (it * 4 + wave) * 512;
        __builtin_amdgcn_global_load_lds(
            (const __attribute__((address_space(1))) void*)(wbf + off + lane * 8),
            (__attribute__((address_space(3))) void*)(&wc[off]), 16, 0, 0);
    }

    bf16x8 bfr[2][6];
    #pragma unroll
    for (int nt = 0; nt < 2; nt++) {
        int token = p0 + nt * 16 + l16;
        #pragma unroll
        for (int k = 0; k < 6; k++)
            bfr[nt][k] = *(const bf16x8*)(xin + (size_t)token * CCH + k * 32 + quad * 8);
    }

    __syncthreads();    // chunk 0 + bfr ready

    #pragma unroll
    for (int ch = 0; ch < 2; ch++) {
        f32x4 acc[6][2];
        #pragma unroll
        for (int m = 0; m < 6; m++)
            #pragma unroll
            for (int nt = 0; nt < 2; nt++) acc[m][nt] = (f32x4){0.f, 0.f, 0.f, 0.f};

        #pragma unroll
        for (int k = 0; k < 6; k++) {
            #pragma unroll
            for (int m = 0; m < 6; m++) {
                bf16x8 afrag = *(const bf16x8*)(wc + ((k * 4 + quad) * 96 + m * 16 + l16) * 8);
                acc[m][0] = __builtin_amdgcn_mfma_f32_16x16x32_bf16(afrag, bfr[0][k], acc[m][0], 0, 0, 0);
                acc[m][1] = __builtin_amdgcn_mfma_f32_16x16x32_bf16(afrag, bfr[1][k], acc[m][1], 0, 0, 0);
            }
        }

        if (ch + 1 < 2) {
            __syncthreads();
            const ushort* wsrc = wbf + (size_t)18432;
            #pragma unroll
            for (int it = 0; it < 9; it++) {
                int off = (it * 4 + wave) * 512;
                __builtin_amdgcn_global_load_lds(
                    (const __attribute__((address_space(1))) void*)(wsrc + off + lane * 8),
                    (__attribute__((address_space(3))) void*)(&wc[off]), 16, 0, 0);
            }
        }

        const int obase = ch * 96;
        #pragma unroll
        for (int m = 0; m < 6; m++) {
            const int o0 = obase + m * 16 + quad * 4;
            float4 bb = *(const float4*)(bias + o0);
            #pragma unroll
            for (int nt = 0; nt < 2; nt++) {
                int token = p0 + nt * 16 + l16;
                int win = token >> 6, t = token & 63;
                float f0 = acc[m][nt][0] + bb.x, f1 = acc[m][nt][1] + bb.y;
                float f2 = acc[m][nt][2] + bb.z, f3 = acc[m][nt][3] + bb.w;
                int b = win / 784, hn = (win / 28) % 28, wn = win % 28;
                int hh = (hn * 8 + (t >> 3) + SHIFT) % HHW;
                int ww = (wn * 8 + (t & 7) + SHIFT) % HHW;
                float* dst = dout + ((size_t)(b * CCH + o0) * HHW + hh) * HHW + ww;
                dst[0] = f0; dst[(size_t)HHW * HHW] = f1;
                dst[2 * (size_t)HHW * HHW] = f2; dst[3 * (size_t)HHW * HHW] = f3;
            }
        }
        if (ch + 1 < 2) __syncthreads();
    }
}

extern "C" void kernel_launch(void* const* d_in, const int* in_sizes, int n_in,
                              void* d_out, int out_size, void* d_ws, size_t ws_size,
                              hipStream_t stream) {
    const float* x      = (const float*)d_in[0];
    const float* w_qkv  = (const float*)d_in[1];
    const float* b_qkv  = (const float*)d_in[2];
    const float* w_proj = (const float*)d_in[3];
    const float* b_proj = (const float*)d_in[4];
    float* out = (float*)d_out;
    ushort* ws = (ushort*)d_ws;

    ushort* X1 = (ushort*)d_out;       // 77 MB bf16 region inside d_out (dead before out-writes)
    ushort* WQ = (ushort*)d_out + QN;  // bf16 qkv weight image in d_out's spare half
    ushort* X2 = ws;                   // [win][t][192] bf16
    ushort* WP = ws + QN;              // bf16 proj weight image

    prep_w      <<<54, 256, 0, stream>>>(w_qkv, WQ, 576);
    prep_x      <<<4 * 28 * 24, 256, 0, stream>>>(x, X1);
    qkv_attn_win<<<NWIN, 384, 0, stream>>>(X1, WQ, b_qkv, X2);
    prep_w      <<<18, 256, 0, stream>>>(w_proj, WP, 192);
    gemm_proj   <<<NTOK / 128, 256, 0, stream>>>(X2, WP, b_proj, out);
}